// Round 2
// baseline (160.515 us; speedup 1.0000x reference)
//
#include <hip/hip_runtime.h>

#define NUM_GRAPHS 512
#define NPG 200      // nodes per graph
#define EPG 3200     // edges per graph
#define NROIS 200    // input feature dim
#define HID 64
#define OUTC 2
#define APITCH 232   // adjacency row pitch (bytes) = 58 dw
#define HPITCH 232   // hpTl row pitch (elements); 464 B = 29*16 -> b128-aligned rows
#define WIMG_ELEMS (7 * 4 * 2 * 64 * 8)   // 28672 ushorts (W hi/lo frag image)
#define WS_NEEDED ((size_t)WIMG_ELEMS * 2)

typedef short v8s __attribute__((ext_vector_type(8)));
typedef float v4f __attribute__((ext_vector_type(4)));

__device__ __forceinline__ unsigned bf16_rne(float f) {
  unsigned u = __float_as_uint(f);
  return (u + 0x7fffu + ((u >> 16) & 1u)) >> 16;
}

// ============ prep: W -> bf16 hi/lo fragment-order image ============
__global__ void prep_wimg(const float* __restrict__ cw, unsigned short* __restrict__ wimg) {
  int idx = blockIdx.x * 256 + threadIdx.x;
  if (idx >= WIMG_ELEMS) return;
  int i    = idx & 7;
  int lane = (idx >> 3) & 63;
  int hl   = (idx >> 9) & 1;
  int nt   = (idx >> 10) & 3;
  int kt   = idx >> 12;
  int k  = kt * 32 + (lane >> 4) * 8 + i;
  int ch = nt * 16 + (lane & 15);
  float f = (k < NROIS) ? cw[k * HID + ch] : 0.f;
  unsigned hi = bf16_rne(f);
  float lo = f - __uint_as_float(hi << 16);
  wimg[idx] = hl ? (unsigned short)(__float_as_uint(lo) >> 16) : (unsigned short)hi;
}

// ============ fused kernel v6 ============
// vs v5: (A) x prefetch issued AFTER wimg loads so the MFMA waitcnt leaves it in
// flight (true 1-deep prefetch); (B) first barrier = raw lgkmcnt(0)+s_barrier (no
// vmcnt drain of edge/x loads); (C) epilogue1 packs node-pairs via VALU DPP and
// writes ds_write_b32 (16/thread, 2-way banks) instead of 32 scattered b16.
// LDS: 48256 (adj) + 29696 (hpTl) + 800 (cnt) + 800 (dinv) + 256 (pool)
//    = 79808 B -> 2 blocks/CU (16 waves).
struct __align__(16) Smem2 {
  unsigned char adj[208 * APITCH];        // (A+I) counts as bytes
  unsigned short hpTl[HID * HPITCH];      // bf16 dinv[src]*h[src][ch], ch-major
  int cnt[NPG];                           // in-degree (edges only; +1 for self-loop)
  float dinv[NPG];
  int pool[HID];
};

__device__ __forceinline__ v8s tobf16(const float4& a, const float4& b) {
  v8s r;
  r[0] = (short)bf16_rne(a.x); r[1] = (short)bf16_rne(a.y);
  r[2] = (short)bf16_rne(a.z); r[3] = (short)bf16_rne(a.w);
  r[4] = (short)bf16_rne(b.x); r[5] = (short)bf16_rne(b.y);
  r[6] = (short)bf16_rne(b.z); r[7] = (short)bf16_rne(b.w);
  return r;
}

// load the wave's x fragment floats for K-tile kt: lane (mi) reads 8 consecutive
// floats x[node][kt*32 + q*8 .. +8).  kt=6,q>=1 would run past col 200 -> zero-fill.
__device__ __forceinline__ void xfetch(const float* __restrict__ x, int base,
                                       int kt, int q, const int* mts, const int* nrow,
                                       float4 xa[2][2]) {
  const int k0 = kt * 32 + q * 8;
  const bool ok = (k0 + 8 <= NROIS);
  #pragma unroll
  for (int mi = 0; mi < 2; ++mi) {
    if (mts[mi] >= 0) {
      if (ok) {
        const float* px = x + (size_t)(base + nrow[mi]) * NROIS + k0;
        xa[mi][0] = *(const float4*)px;
        xa[mi][1] = *(const float4*)(px + 4);
      } else {
        xa[mi][0] = make_float4(0.f, 0.f, 0.f, 0.f);
        xa[mi][1] = make_float4(0.f, 0.f, 0.f, 0.f);
      }
    }
  }
}

__global__ __launch_bounds__(512, 4)
void gcn_fused6(const float* __restrict__ x,
                const int* __restrict__ ei,
                const unsigned short* __restrict__ wimg,
                const float* __restrict__ cb,
                const float* __restrict__ lw,
                const float* __restrict__ lb,
                float* __restrict__ out,
                int Etot) {
  __shared__ Smem2 s;
  const int g = blockIdx.x;
  const int tid = threadIdx.x;
  const int base = g * NPG;
  const int ebase = g * EPG;
  const int lane = tid & 63;
  const int w = __builtin_amdgcn_readfirstlane(tid >> 6);  // 0..7
  const int ml = tid & 15;
  const int q  = (tid >> 4) & 3;

  int mts[2];
  mts[0] = w;
  mts[1] = (w < 5) ? 8 + w : -1;
  int nrow[2];                       // clamped row index for x loads (junk discarded)
  #pragma unroll
  for (int mi = 0; mi < 2; ++mi) {
    int node = mts[mi] * 16 + ml;
    nrow[mi] = (node < NPG) ? node : 0;
  }

  // ---- startup: issue edge loads + x-tile0 fragment loads; zero adj/cnt/pool ----
  int esrc[7], edst[7];
  #pragma unroll
  for (int r = 0; r < 7; ++r) {
    int e = tid + r * 512;
    esrc[r] = -1; edst[r] = 0;
    if (e < EPG) {
      esrc[r] = ei[ebase + e] - base;
      edst[r] = ei[Etot + ebase + e] - base;
    }
  }
  float4 xa[2][2];
  xfetch(x, base, 0, q, mts, nrow, xa);
  {
    uint4* z = (uint4*)s.adj;
    const uint4 z4 = {0u, 0u, 0u, 0u};
    #pragma unroll
    for (int i = 0; i < 6; ++i) {
      int idx = tid + i * 512;
      if (idx < (208 * APITCH) / 16) z[idx] = z4;
    }
    if (tid < NPG) s.cnt[tid] = 0;
    if (tid < HID) s.pool[tid] = 0;   // relu >= 0 -> 0 is identity for max
  }
  // (B) fence only the LDS zero-stores; leave edge/x global loads in flight.
  asm volatile("s_waitcnt lgkmcnt(0)\n\ts_barrier" ::: "memory");

  // ---- scatter (A+I) counts + in-degree (fire-and-forget ds atomics; they drain
  //      during GEMM1 and are fenced by the barrier AFTER it) ----
  {
    unsigned* adjW = (unsigned*)s.adj;
    #pragma unroll
    for (int r = 0; r < 7; ++r) {
      if (esrc[r] >= 0) {
        int idx = edst[r] * APITCH + esrc[r];
        atomicAdd(&adjW[idx >> 2], 1u << ((idx & 3) * 8));
        atomicAdd(&s.cnt[edst[r]], 1);
      }
    }
    if (tid < NPG) {                      // self-loop diagonal (degree handled as cnt+1)
      int idx = tid * APITCH + tid;
      atomicAdd(&adjW[idx >> 2], 1u << ((idx & 3) * 8));
    }
  }

  // ---- GEMM1: H = X @ W  (x direct-from-global, 1-deep prefetch, NO barriers) ----
  v4f acc[2][4];
  #pragma unroll
  for (int a = 0; a < 2; ++a)
    #pragma unroll
    for (int b = 0; b < 4; ++b)
      acc[a][b] = (v4f){0.f, 0.f, 0.f, 0.f};

  for (int kt = 0; kt < 7; ++kt) {
    // convert current fragments first -> frees xa for the next prefetch
    v8s xh2[2];
    #pragma unroll
    for (int mi = 0; mi < 2; ++mi)
      if (mts[mi] >= 0) xh2[mi] = tobf16(xa[mi][0], xa[mi][1]);

    // (A) wimg loads FIRST ...
    v8s whi[4], wlo[4];
    #pragma unroll
    for (int nt = 0; nt < 4; ++nt) {
      const unsigned short* pw = wimg + (size_t)(((kt * 4 + nt) * 2) * 64 + lane) * 8;
      whi[nt] = *(const v8s*)pw;                 // coalesced 1KB wave load (L2/L3-hot)
      wlo[nt] = *(const v8s*)(pw + 64 * 8);
    }
    // ... THEN the x prefetch: the MFMA waitcnt (wimg) leaves these in flight.
    if (kt < 6) xfetch(x, base, kt + 1, q, mts, nrow, xa);

    #pragma unroll
    for (int mi = 0; mi < 2; ++mi) {
      if (mts[mi] >= 0) {
        #pragma unroll
        for (int nt = 0; nt < 4; ++nt) {
          acc[mi][nt] = __builtin_amdgcn_mfma_f32_16x16x32_bf16(wlo[nt], xh2[mi], acc[mi][nt], 0, 0, 0);
          acc[mi][nt] = __builtin_amdgcn_mfma_f32_16x16x32_bf16(whi[nt], xh2[mi], acc[mi][nt], 0, 0, 0);
        }
      }
    }
  }
  __syncthreads();    // scatter + cnt complete, GEMM1 accs final

  // ---- dinv table (for epilogue2) + pad-zero hpTl cols [200,232) + epilogue1 ----
  if (tid < NPG) s.dinv[tid] = rsqrtf((float)(s.cnt[tid] + 1));
  {
    int ch = tid >> 3, grp = tid & 7;
    *(uint2*)&s.hpTl[ch * HPITCH + 200 + grp * 4] = (uint2){0u, 0u};
  }
  // (C) epilogue1: node-pair pack via DPP quad_perm(lane^1), b32 writes.
  // Even-ml lanes write r in {0,1}, odd-ml lanes write r in {2,3}; each dword
  // holds (node even -> low half, node odd -> high half) for one ch.
  #pragma unroll
  for (int mi = 0; mi < 2; ++mi) {
    if (mts[mi] >= 0) {
      const int node = mts[mi] * 16 + ml;
      const bool nvalid = (node < NPG);
      const float dv = nvalid ? rsqrtf((float)(s.cnt[node] + 1)) : 0.f;  // == s.dinv
      #pragma unroll
      for (int nt = 0; nt < 4; ++nt) {
        unsigned b[4], pb[4];
        #pragma unroll
        for (int r = 0; r < 4; ++r) b[r] = bf16_rne(dv * acc[mi][nt][r]);
        #pragma unroll
        for (int r = 0; r < 4; ++r)
          pb[r] = (unsigned)__builtin_amdgcn_mov_dpp((int)b[r], 0xB1, 0xF, 0xF, true);
        if (nvalid) {                       // pair (node^1) shares validity (NPG even)
          const int nb = node & ~1;
          const int r0 = (ml & 1) ? 2 : 0;
          #pragma unroll
          for (int t = 0; t < 2; ++t) {
            const int r = r0 + t;
            const int ch = nt * 16 + q * 4 + r;
            const unsigned lo = (ml & 1) ? pb[r] : b[r];
            const unsigned hi = (ml & 1) ? b[r] : pb[r];
            *(unsigned*)&s.hpTl[ch * HPITCH + nb] = lo | (hi << 16);
          }
        }
      }
    }
  }
  __syncthreads();

  // ---- GEMM2: AGG = (A+I) @ hp (counts exact in bf16) ----
  {
    float cbv[4];                       // hoisted: global latency hidden under GEMM2
    #pragma unroll
    for (int nt = 0; nt < 4; ++nt) cbv[nt] = cb[nt * 16 + ml];

    v4f acc2[2][4];
    #pragma unroll
    for (int a = 0; a < 2; ++a)
      #pragma unroll
      for (int b = 0; b < 4; ++b)
        acc2[a][b] = (v4f){0.f, 0.f, 0.f, 0.f};

    for (int kt = 0; kt < 7; ++kt) {
      const int k0 = kt * 32 + q * 8;

      v8s bf[4];
      #pragma unroll
      for (int nt = 0; nt < 4; ++nt)
        bf[nt] = *(const v8s*)&s.hpTl[(nt * 16 + ml) * HPITCH + k0];

      #pragma unroll
      for (int mi = 0; mi < 2; ++mi) {
        if (mts[mi] >= 0) {
          const int row = mts[mi] * 16 + ml;
          const uint2 dd = *(const uint2*)&s.adj[row * APITCH + k0];
          v8s af;
          #pragma unroll
          for (int i = 0; i < 4; ++i) {
            af[i]     = (short)(__float_as_uint((float)((dd.x >> (8 * i)) & 0xffu)) >> 16);
            af[i + 4] = (short)(__float_as_uint((float)((dd.y >> (8 * i)) & 0xffu)) >> 16);
          }
          #pragma unroll
          for (int nt = 0; nt < 4; ++nt)
            acc2[mi][nt] = __builtin_amdgcn_mfma_f32_16x16x32_bf16(af, bf[nt], acc2[mi][nt], 0, 0, 0);
        }
      }
    }

    // epilogue2: relu(dinv[dst]*agg + cb) -> max-pool
    float mx[4] = {0.f, 0.f, 0.f, 0.f};
    #pragma unroll
    for (int mi = 0; mi < 2; ++mi) {
      if (mts[mi] >= 0) {
        #pragma unroll
        for (int r = 0; r < 4; ++r) {
          const int row = mts[mi] * 16 + q * 4 + r;
          if (row < NPG) {
            const float dv = s.dinv[row];
            #pragma unroll
            for (int nt = 0; nt < 4; ++nt) {
              float v = fmaxf(fmaf(dv, acc2[mi][nt][r], cbv[nt]), 0.f);
              mx[nt] = fmaxf(mx[nt], v);
            }
          }
        }
      }
    }
    #pragma unroll
    for (int nt = 0; nt < 4; ++nt) {
      mx[nt] = fmaxf(mx[nt], __shfl_xor(mx[nt], 16));
      mx[nt] = fmaxf(mx[nt], __shfl_xor(mx[nt], 32));
    }
    if (q == 0 && (lane >> 5) == 0) {
      #pragma unroll
      for (int nt = 0; nt < 4; ++nt)
        atomicMax(&s.pool[nt * 16 + ml], __float_as_int(mx[nt]));
    }
  }
  __syncthreads();

  // ---- write x_pool and out ----
  if (tid < HID) {
    const float xp = __int_as_float(s.pool[tid]);
    out[NUM_GRAPHS * OUTC + g * HID + tid] = xp;
    float p0 = xp * lw[tid * 2 + 0];
    float p1 = xp * lw[tid * 2 + 1];
    #pragma unroll
    for (int off = 32; off > 0; off >>= 1) {
      p0 += __shfl_down(p0, off);
      p1 += __shfl_down(p1, off);
    }
    if (tid == 0) {
      out[g * OUTC + 0] = p0 + lb[0];
      out[g * OUTC + 1] = p1 + lb[1];
    }
  }
}

// ============ fallback (ws too small): fused kernel, inline W convert ============
struct __align__(16) SmemF {
  unsigned char adj[208 * APITCH];
  unsigned short hpT[HID * HPITCH];
  float dinv[NPG];
  int cnt[NPG];
  int pool[HID];
};

__global__ __launch_bounds__(512, 4)
void gcn_fused_fb(const float* __restrict__ x,
                  const int* __restrict__ ei,
                  const float* __restrict__ cw,
                  const float* __restrict__ cb,
                  const float* __restrict__ lw,
                  const float* __restrict__ lb,
                  float* __restrict__ out,
                  int Etot) {
  __shared__ SmemF s;
  const int g = blockIdx.x;
  const int tid = threadIdx.x;
  const int base = g * NPG;
  const int ebase = g * EPG;
  const int lane = tid & 63;
  const int w = __builtin_amdgcn_readfirstlane(tid >> 6);
  const int ml = tid & 15;
  const int q  = (tid >> 4) & 3;

  {
    uint4* z = (uint4*)&s;
    const uint4 z4 = {0u, 0u, 0u, 0u};
    #pragma unroll
    for (int i = 0; i < 10; ++i) {
      int idx = tid + i * 512;
      if (idx < (208 * APITCH + HID * HPITCH * 2) / 16) z[idx] = z4;
    }
    if (tid < NPG) s.cnt[tid] = 0;
    if (tid < HID) s.pool[tid] = 0;
  }
  __syncthreads();

  int esrc[7], edst[7];
  #pragma unroll
  for (int r = 0; r < 7; ++r) {
    int e = tid + r * 512;
    esrc[r] = -1; edst[r] = 0;
    if (e < EPG) {
      esrc[r] = ei[ebase + e] - base;
      edst[r] = ei[Etot + ebase + e] - base;
      atomicAdd(&s.cnt[edst[r]], 1);
    }
  }
  __syncthreads();

  if (tid < NPG) s.dinv[tid] = rsqrtf((float)(s.cnt[tid] + 1));

  {
    unsigned* adjW = (unsigned*)s.adj;
    #pragma unroll
    for (int r = 0; r < 7; ++r) {
      if (esrc[r] >= 0) {
        int idx = edst[r] * APITCH + esrc[r];
        atomicAdd(&adjW[idx >> 2], 1u << ((idx & 3) * 8));
      }
    }
    if (tid < NPG) {
      int idx = tid * APITCH + tid;
      atomicAdd(&adjW[idx >> 2], 1u << ((idx & 3) * 8));
    }
  }
  __syncthreads();

  {
    int mts[2];
    mts[0] = w;
    mts[1] = (w < 5) ? 8 + w : -1;
    v4f acc[2][4];
    #pragma unroll
    for (int a = 0; a < 2; ++a)
      #pragma unroll
      for (int b = 0; b < 4; ++b)
        acc[a][b] = (v4f){0.f, 0.f, 0.f, 0.f};

    for (int kt = 0; kt < 7; ++kt) {
      const int k0 = kt * 32 + q * 8;
      const bool kok = (k0 < NROIS);
      v8s bhi[4], blo[4];
      #pragma unroll
      for (int nt = 0; nt < 4; ++nt) {
        #pragma unroll
        for (int i = 0; i < 8; ++i) {
          float f = kok ? cw[(k0 + i) * HID + nt * 16 + ml] : 0.f;
          unsigned hb = bf16_rne(f);
          float lo = f - __uint_as_float(hb << 16);
          bhi[nt][i] = (short)hb;
          blo[nt][i] = (short)(__float_as_uint(lo) >> 16);
        }
      }
      #pragma unroll
      for (int mi = 0; mi < 2; ++mi) {
        if (mts[mi] >= 0) {
          const int row = mts[mi] * 16 + ml;
          v8s ahi, alo;
          if (kok && row < NPG) {
            const float* px = x + (size_t)(base + row) * NROIS + k0;
            const float4 f0 = *(const float4*)px;
            const float4 f1 = *(const float4*)(px + 4);
            const float ff[8] = {f0.x, f0.y, f0.z, f0.w, f1.x, f1.y, f1.z, f1.w};
            #pragma unroll
            for (int i = 0; i < 8; ++i) {
              unsigned u = __float_as_uint(ff[i]);
              unsigned hb = u >> 16;
              float lo = ff[i] - __uint_as_float(hb << 16);
              ahi[i] = (short)hb;
              alo[i] = (short)(__float_as_uint(lo) >> 16);
            }
          } else {
            #pragma unroll
            for (int i = 0; i < 8; ++i) { ahi[i] = 0; alo[i] = 0; }
          }
          #pragma unroll
          for (int nt = 0; nt < 4; ++nt) {
            acc[mi][nt] = __builtin_amdgcn_mfma_f32_16x16x32_bf16(ahi, blo[nt], acc[mi][nt], 0, 0, 0);
            acc[mi][nt] = __builtin_amdgcn_mfma_f32_16x16x32_bf16(alo, bhi[nt], acc[mi][nt], 0, 0, 0);
            acc[mi][nt] = __builtin_amdgcn_mfma_f32_16x16x32_bf16(ahi, bhi[nt], acc[mi][nt], 0, 0, 0);
          }
        }
      }
    }
    #pragma unroll
    for (int mi = 0; mi < 2; ++mi) {
      if (mts[mi] >= 0) {
        #pragma unroll
        for (int r = 0; r < 4; ++r) {
          const int row = mts[mi] * 16 + q * 4 + r;
          if (row < NPG) {
            const float dv = s.dinv[row];
            #pragma unroll
            for (int nt = 0; nt < 4; ++nt)
              s.hpT[(nt * 16 + ml) * HPITCH + row] =
                  (unsigned short)bf16_rne(dv * acc[mi][nt][r]);
          }
        }
      }
    }
  }
  __syncthreads();

  {
    int mts[2];
    mts[0] = w;
    mts[1] = (w < 5) ? 8 + w : -1;
    v4f acc2[2][4];
    #pragma unroll
    for (int a = 0; a < 2; ++a)
      #pragma unroll
      for (int b = 0; b < 4; ++b)
        acc2[a][b] = (v4f){0.f, 0.f, 0.f, 0.f};

    for (int kt = 0; kt < 7; ++kt) {
      const int k0 = kt * 32 + q * 8;
      v8s bf[4];
      #pragma unroll
      for (int nt = 0; nt < 4; ++nt)
        bf[nt] = *(const v8s*)&s.hpT[(nt * 16 + ml) * HPITCH + k0];
      #pragma unroll
      for (int mi = 0; mi < 2; ++mi) {
        if (mts[mi] >= 0) {
          const int row = mts[mi] * 16 + ml;
          const uint2 dd = *(const uint2*)&s.adj[row * APITCH + k0];
          v8s af;
          #pragma unroll
          for (int i = 0; i < 4; ++i) {
            af[i]     = (short)(__float_as_uint((float)((dd.x >> (8 * i)) & 0xffu)) >> 16);
            af[i + 4] = (short)(__float_as_uint((float)((dd.y >> (8 * i)) & 0xffu)) >> 16);
          }
          #pragma unroll
          for (int nt = 0; nt < 4; ++nt)
            acc2[mi][nt] = __builtin_amdgcn_mfma_f32_16x16x32_bf16(af, bf[nt], acc2[mi][nt], 0, 0, 0);
        }
      }
    }

    float cbv[4];
    #pragma unroll
    for (int nt = 0; nt < 4; ++nt) cbv[nt] = cb[nt * 16 + ml];
    float mx[4] = {0.f, 0.f, 0.f, 0.f};
    #pragma unroll
    for (int mi = 0; mi < 2; ++mi) {
      if (mts[mi] >= 0) {
        #pragma unroll
        for (int r = 0; r < 4; ++r) {
          const int row = mts[mi] * 16 + q * 4 + r;
          if (row < NPG) {
            const float dv = s.dinv[row];
            #pragma unroll
            for (int nt = 0; nt < 4; ++nt) {
              float v = fmaxf(fmaf(dv, acc2[mi][nt][r], cbv[nt]), 0.f);
              mx[nt] = fmaxf(mx[nt], v);
            }
          }
        }
      }
    }
    #pragma unroll
    for (int nt = 0; nt < 4; ++nt) {
      mx[nt] = fmaxf(mx[nt], __shfl_xor(mx[nt], 16));
      mx[nt] = fmaxf(mx[nt], __shfl_xor(mx[nt], 32));
    }
    if (q == 0 && (lane >> 5) == 0) {
      #pragma unroll
      for (int nt = 0; nt < 4; ++nt)
        atomicMax(&s.pool[nt * 16 + ml], __float_as_int(mx[nt]));
    }
  }
  __syncthreads();

  if (tid < HID) {
    const float xp = __int_as_float(s.pool[tid]);
    out[NUM_GRAPHS * OUTC + g * HID + tid] = xp;
    float p0 = xp * lw[tid * 2 + 0];
    float p1 = xp * lw[tid * 2 + 1];
    #pragma unroll
    for (int off = 32; off > 0; off >>= 1) {
      p0 += __shfl_down(p0, off);
      p1 += __shfl_down(p1, off);
    }
    if (tid == 0) {
      out[g * OUTC + 0] = p0 + lb[0];
      out[g * OUTC + 1] = p1 + lb[1];
    }
  }
}

extern "C" void kernel_launch(void* const* d_in, const int* in_sizes, int n_in,
                              void* d_out, int out_size, void* d_ws, size_t ws_size,
                              hipStream_t stream) {
  const float* x  = (const float*)d_in[0];
  const int*   ei = (const int*)d_in[1];
  // d_in[2] = batch (node/200 by construction; unused)
  const float* cw = (const float*)d_in[3];
  const float* cb = (const float*)d_in[4];
  const float* lw = (const float*)d_in[5];
  const float* lb = (const float*)d_in[6];
  const int Etot = in_sizes[1] / 2;

  if (ws_size >= WS_NEEDED) {
    unsigned short* wimg = (unsigned short*)d_ws;
    prep_wimg<<<(WIMG_ELEMS + 255) / 256, 256, 0, stream>>>(cw, wimg);
    gcn_fused6<<<NUM_GRAPHS, 512, 0, stream>>>(x, ei, wimg, cb, lw, lb,
                                               (float*)d_out, Etot);
  } else {
    gcn_fused_fb<<<NUM_GRAPHS, 512, 0, stream>>>(x, ei, cw, cb, lw, lb,
                                                 (float*)d_out, Etot);
  }
}

// Round 4
// 157.379 us; speedup vs baseline: 1.0199x; 1.0199x over previous
//
#include <hip/hip_runtime.h>

#define NUM_GRAPHS 512
#define NPG 200      // nodes per graph
#define EPG 3200     // edges per graph
#define NROIS 200    // input feature dim
#define HID 64
#define OUTC 2
#define APITCH 232   // adjacency row pitch (bytes) = 58 dw
#define HPITCH 232   // hpTl row pitch (elements); 464 B = 29*16 -> b128-aligned rows
#define WIMG_ELEMS (7 * 4 * 2 * 64 * 8)   // 28672 ushorts (W hi/lo frag image)
#define WS_NEEDED ((size_t)WIMG_ELEMS * 2)

typedef short v8s __attribute__((ext_vector_type(8)));
typedef float v4f __attribute__((ext_vector_type(4)));

__device__ __forceinline__ unsigned bf16_rne(float f) {
  unsigned u = __float_as_uint(f);
  return (u + 0x7fffu + ((u >> 16) & 1u)) >> 16;
}

// ============ prep: W -> bf16 hi/lo fragment-order image ============
__global__ void prep_wimg(const float* __restrict__ cw, unsigned short* __restrict__ wimg) {
  int idx = blockIdx.x * 256 + threadIdx.x;
  if (idx >= WIMG_ELEMS) return;
  int i    = idx & 7;
  int lane = (idx >> 3) & 63;
  int hl   = (idx >> 9) & 1;
  int nt   = (idx >> 10) & 3;
  int kt   = idx >> 12;
  int k  = kt * 32 + (lane >> 4) * 8 + i;
  int ch = nt * 16 + (lane & 15);
  float f = (k < NROIS) ? cw[k * HID + ch] : 0.f;
  unsigned hi = bf16_rne(f);
  float lo = f - __uint_as_float(hi << 16);
  wimg[idx] = hl ? (unsigned short)(__float_as_uint(lo) >> 16) : (unsigned short)hi;
}

// ============ fused kernel v7 ============
// v5 structure (fastest measured) + ONE change: W fragments register-double-buffered
// so W[kt] is loaded a full kt-iteration before its MFMAs (per-kt L2 latency off the
// critical path). Numerics identical to v5 (same load values, same MFMA order).
// LDS: 48256 (adj) + 29696 (hpTl) + 800 (cnt) + 800 (dinv) + 256 (pool)
//    = 79808 B -> 2 blocks/CU (16 waves).
struct __align__(16) Smem2 {
  unsigned char adj[208 * APITCH];        // (A+I) counts as bytes
  unsigned short hpTl[HID * HPITCH];      // bf16 dinv[src]*h[src][ch], ch-major
  int cnt[NPG];                           // in-degree (edges only; +1 for self-loop)
  float dinv[NPG];
  int pool[HID];
};

__device__ __forceinline__ v8s tobf16(const float4& a, const float4& b) {
  v8s r;
  r[0] = (short)bf16_rne(a.x); r[1] = (short)bf16_rne(a.y);
  r[2] = (short)bf16_rne(a.z); r[3] = (short)bf16_rne(a.w);
  r[4] = (short)bf16_rne(b.x); r[5] = (short)bf16_rne(b.y);
  r[6] = (short)bf16_rne(b.z); r[7] = (short)bf16_rne(b.w);
  return r;
}

// load the wave's x fragment floats for K-tile kt: lane (mi) reads 8 consecutive
// floats x[node][kt*32 + q*8 .. +8).  kt=6,q>=1 would run past col 200 -> zero-fill.
__device__ __forceinline__ void xfetch(const float* __restrict__ x, int base,
                                       int kt, int q, const int* mts, const int* nrow,
                                       float4 xa[2][2]) {
  const int k0 = kt * 32 + q * 8;
  const bool ok = (k0 + 8 <= NROIS);
  #pragma unroll
  for (int mi = 0; mi < 2; ++mi) {
    if (mts[mi] >= 0) {
      if (ok) {
        const float* px = x + (size_t)(base + nrow[mi]) * NROIS + k0;
        xa[mi][0] = *(const float4*)px;
        xa[mi][1] = *(const float4*)(px + 4);
      } else {
        xa[mi][0] = make_float4(0.f, 0.f, 0.f, 0.f);
        xa[mi][1] = make_float4(0.f, 0.f, 0.f, 0.f);
      }
    }
  }
}

__global__ __launch_bounds__(512, 4)
void gcn_fused7(const float* __restrict__ x,
                const int* __restrict__ ei,
                const unsigned short* __restrict__ wimg,
                const float* __restrict__ cb,
                const float* __restrict__ lw,
                const float* __restrict__ lb,
                float* __restrict__ out,
                int Etot) {
  __shared__ Smem2 s;
  const int g = blockIdx.x;
  const int tid = threadIdx.x;
  const int base = g * NPG;
  const int ebase = g * EPG;
  const int lane = tid & 63;
  const int w = __builtin_amdgcn_readfirstlane(tid >> 6);  // 0..7
  const int ml = tid & 15;
  const int q  = (tid >> 4) & 3;

  int mts[2];
  mts[0] = w;
  mts[1] = (w < 5) ? 8 + w : -1;
  int nrow[2];                       // clamped row index for x loads (junk discarded)
  #pragma unroll
  for (int mi = 0; mi < 2; ++mi) {
    int node = mts[mi] * 16 + ml;
    nrow[mi] = (node < NPG) ? node : 0;
  }

  // ---- startup: issue edge loads + x-tile0 fragment loads; zero adj/cnt/pool ----
  int esrc[7], edst[7];
  #pragma unroll
  for (int r = 0; r < 7; ++r) {
    int e = tid + r * 512;
    esrc[r] = -1; edst[r] = 0;
    if (e < EPG) {
      esrc[r] = ei[ebase + e] - base;
      edst[r] = ei[Etot + ebase + e] - base;
    }
  }
  float4 xa[2][2];
  xfetch(x, base, 0, q, mts, nrow, xa);
  {
    uint4* z = (uint4*)s.adj;
    const uint4 z4 = {0u, 0u, 0u, 0u};
    #pragma unroll
    for (int i = 0; i < 6; ++i) {
      int idx = tid + i * 512;
      if (idx < (208 * APITCH) / 16) z[idx] = z4;
    }
    if (tid < NPG) s.cnt[tid] = 0;
    if (tid < HID) s.pool[tid] = 0;   // relu >= 0 -> 0 is identity for max
  }
  __syncthreads();

  // ---- scatter (A+I) counts + in-degree (fire-and-forget ds atomics; they drain
  //      during GEMM1 and are fenced by the barrier AFTER it) ----
  {
    unsigned* adjW = (unsigned*)s.adj;
    #pragma unroll
    for (int r = 0; r < 7; ++r) {
      if (esrc[r] >= 0) {
        int idx = edst[r] * APITCH + esrc[r];
        atomicAdd(&adjW[idx >> 2], 1u << ((idx & 3) * 8));
        atomicAdd(&s.cnt[edst[r]], 1);
      }
    }
    if (tid < NPG) {                      // self-loop diagonal (degree handled as cnt+1)
      int idx = tid * APITCH + tid;
      atomicAdd(&adjW[idx >> 2], 1u << ((idx & 3) * 8));
    }
  }

  // ---- GEMM1: H = X @ W  (x direct-from-global 1-deep; W regs double-buffered) ----
  v4f acc[2][4];
  #pragma unroll
  for (int a = 0; a < 2; ++a)
    #pragma unroll
    for (int b = 0; b < 4; ++b)
      acc[a][b] = (v4f){0.f, 0.f, 0.f, 0.f};

  // preload W tile 0 into buffer 0
  v8s whi[2][4], wlo[2][4];
  #pragma unroll
  for (int nt = 0; nt < 4; ++nt) {
    const unsigned short* pw = wimg + (size_t)((nt * 2) * 64 + lane) * 8;
    whi[0][nt] = *(const v8s*)pw;
    wlo[0][nt] = *(const v8s*)(pw + 64 * 8);
  }

  #pragma unroll
  for (int kt = 0; kt < 7; ++kt) {
    const int cur = kt & 1, nxt = cur ^ 1;
    // convert current x fragments first -> frees xa for the next prefetch
    v8s xh2[2];
    #pragma unroll
    for (int mi = 0; mi < 2; ++mi)
      if (mts[mi] >= 0) xh2[mi] = tobf16(xa[mi][0], xa[mi][1]);
    if (kt < 6) xfetch(x, base, kt + 1, q, mts, nrow, xa);   // in flight during MFMAs
    if (kt < 6) {
      #pragma unroll
      for (int nt = 0; nt < 4; ++nt) {   // W[kt+1]: a full iteration of slack
        const unsigned short* pw = wimg + (size_t)((((kt + 1) * 4 + nt) * 2) * 64 + lane) * 8;
        whi[nxt][nt] = *(const v8s*)pw;
        wlo[nxt][nt] = *(const v8s*)(pw + 64 * 8);
      }
    }
    #pragma unroll
    for (int mi = 0; mi < 2; ++mi) {
      if (mts[mi] >= 0) {
        #pragma unroll
        for (int nt = 0; nt < 4; ++nt) {
          acc[mi][nt] = __builtin_amdgcn_mfma_f32_16x16x32_bf16(wlo[cur][nt], xh2[mi], acc[mi][nt], 0, 0, 0);
          acc[mi][nt] = __builtin_amdgcn_mfma_f32_16x16x32_bf16(whi[cur][nt], xh2[mi], acc[mi][nt], 0, 0, 0);
        }
      }
    }
  }
  __syncthreads();    // scatter + cnt complete, GEMM1 accs final

  // ---- dinv table (for epilogue2) + pad-zero hpTl cols [200,232) + epilogue1 ----
  if (tid < NPG) s.dinv[tid] = rsqrtf((float)(s.cnt[tid] + 1));
  {
    int ch = tid >> 3, grp = tid & 7;
    *(uint2*)&s.hpTl[ch * HPITCH + 200 + grp * 4] = (uint2){0u, 0u};
  }
  #pragma unroll
  for (int mi = 0; mi < 2; ++mi) {
    if (mts[mi] >= 0) {
      const int node = mts[mi] * 16 + ml;
      if (node < NPG) {
        const float dv = rsqrtf((float)(s.cnt[node] + 1));   // bitwise == s.dinv[node]
        #pragma unroll
        for (int nt = 0; nt < 4; ++nt) {
          #pragma unroll
          for (int r = 0; r < 4; ++r) {
            const int ch = nt * 16 + q * 4 + r;
            s.hpTl[ch * HPITCH + node] = (unsigned short)bf16_rne(dv * acc[mi][nt][r]);
          }
        }
      }
    }
  }
  __syncthreads();

  // ---- GEMM2: AGG = (A+I) @ hp (counts exact in bf16) ----
  {
    v4f acc2[2][4];
    #pragma unroll
    for (int a = 0; a < 2; ++a)
      #pragma unroll
      for (int b = 0; b < 4; ++b)
        acc2[a][b] = (v4f){0.f, 0.f, 0.f, 0.f};

    for (int kt = 0; kt < 7; ++kt) {
      const int k0 = kt * 32 + q * 8;

      v8s bf[4];
      #pragma unroll
      for (int nt = 0; nt < 4; ++nt)
        bf[nt] = *(const v8s*)&s.hpTl[(nt * 16 + ml) * HPITCH + k0];

      #pragma unroll
      for (int mi = 0; mi < 2; ++mi) {
        if (mts[mi] >= 0) {
          const int row = mts[mi] * 16 + ml;
          const uint2 dd = *(const uint2*)&s.adj[row * APITCH + k0];
          v8s af;
          #pragma unroll
          for (int i = 0; i < 4; ++i) {
            af[i]     = (short)(__float_as_uint((float)((dd.x >> (8 * i)) & 0xffu)) >> 16);
            af[i + 4] = (short)(__float_as_uint((float)((dd.y >> (8 * i)) & 0xffu)) >> 16);
          }
          #pragma unroll
          for (int nt = 0; nt < 4; ++nt)
            acc2[mi][nt] = __builtin_amdgcn_mfma_f32_16x16x32_bf16(af, bf[nt], acc2[mi][nt], 0, 0, 0);
        }
      }
    }

    // epilogue2: relu(dinv[dst]*agg + cb) -> max-pool
    float cbv[4];
    #pragma unroll
    for (int nt = 0; nt < 4; ++nt) cbv[nt] = cb[nt * 16 + ml];
    float mx[4] = {0.f, 0.f, 0.f, 0.f};
    #pragma unroll
    for (int mi = 0; mi < 2; ++mi) {
      if (mts[mi] >= 0) {
        #pragma unroll
        for (int r = 0; r < 4; ++r) {
          const int row = mts[mi] * 16 + q * 4 + r;
          if (row < NPG) {
            const float dv = s.dinv[row];
            #pragma unroll
            for (int nt = 0; nt < 4; ++nt) {
              float v = fmaxf(fmaf(dv, acc2[mi][nt][r], cbv[nt]), 0.f);
              mx[nt] = fmaxf(mx[nt], v);
            }
          }
        }
      }
    }
    #pragma unroll
    for (int nt = 0; nt < 4; ++nt) {
      mx[nt] = fmaxf(mx[nt], __shfl_xor(mx[nt], 16));
      mx[nt] = fmaxf(mx[nt], __shfl_xor(mx[nt], 32));
    }
    if (q == 0 && (lane >> 5) == 0) {
      #pragma unroll
      for (int nt = 0; nt < 4; ++nt)
        atomicMax(&s.pool[nt * 16 + ml], __float_as_int(mx[nt]));
    }
  }
  __syncthreads();

  // ---- write x_pool and out ----
  if (tid < HID) {
    const float xp = __int_as_float(s.pool[tid]);
    out[NUM_GRAPHS * OUTC + g * HID + tid] = xp;
    float p0 = xp * lw[tid * 2 + 0];
    float p1 = xp * lw[tid * 2 + 1];
    #pragma unroll
    for (int off = 32; off > 0; off >>= 1) {
      p0 += __shfl_down(p0, off);
      p1 += __shfl_down(p1, off);
    }
    if (tid == 0) {
      out[g * OUTC + 0] = p0 + lb[0];
      out[g * OUTC + 1] = p1 + lb[1];
    }
  }
}

// ============ fallback (ws too small): fused kernel, inline W convert ============
struct __align__(16) SmemF {
  unsigned char adj[208 * APITCH];
  unsigned short hpT[HID * HPITCH];
  float dinv[NPG];
  int cnt[NPG];
  int pool[HID];
};

__global__ __launch_bounds__(512, 4)
void gcn_fused_fb(const float* __restrict__ x,
                  const int* __restrict__ ei,
                  const float* __restrict__ cw,
                  const float* __restrict__ cb,
                  const float* __restrict__ lw,
                  const float* __restrict__ lb,
                  float* __restrict__ out,
                  int Etot) {
  __shared__ SmemF s;
  const int g = blockIdx.x;
  const int tid = threadIdx.x;
  const int base = g * NPG;
  const int ebase = g * EPG;
  const int lane = tid & 63;
  const int w = __builtin_amdgcn_readfirstlane(tid >> 6);
  const int ml = tid & 15;
  const int q  = (tid >> 4) & 3;

  {
    uint4* z = (uint4*)&s;
    const uint4 z4 = {0u, 0u, 0u, 0u};
    #pragma unroll
    for (int i = 0; i < 10; ++i) {
      int idx = tid + i * 512;
      if (idx < (208 * APITCH + HID * HPITCH * 2) / 16) z[idx] = z4;
    }
    if (tid < NPG) s.cnt[tid] = 0;
    if (tid < HID) s.pool[tid] = 0;
  }
  __syncthreads();

  int esrc[7], edst[7];
  #pragma unroll
  for (int r = 0; r < 7; ++r) {
    int e = tid + r * 512;
    esrc[r] = -1; edst[r] = 0;
    if (e < EPG) {
      esrc[r] = ei[ebase + e] - base;
      edst[r] = ei[Etot + ebase + e] - base;
      atomicAdd(&s.cnt[edst[r]], 1);
    }
  }
  __syncthreads();

  if (tid < NPG) s.dinv[tid] = rsqrtf((float)(s.cnt[tid] + 1));

  {
    unsigned* adjW = (unsigned*)s.adj;
    #pragma unroll
    for (int r = 0; r < 7; ++r) {
      if (esrc[r] >= 0) {
        int idx = edst[r] * APITCH + esrc[r];
        atomicAdd(&adjW[idx >> 2], 1u << ((idx & 3) * 8));
      }
    }
    if (tid < NPG) {
      int idx = tid * APITCH + tid;
      atomicAdd(&adjW[idx >> 2], 1u << ((idx & 3) * 8));
    }
  }
  __syncthreads();

  {
    int mts[2];
    mts[0] = w;
    mts[1] = (w < 5) ? 8 + w : -1;
    v4f acc[2][4];
    #pragma unroll
    for (int a = 0; a < 2; ++a)
      #pragma unroll
      for (int b = 0; b < 4; ++b)
        acc[a][b] = (v4f){0.f, 0.f, 0.f, 0.f};

    for (int kt = 0; kt < 7; ++kt) {
      const int k0 = kt * 32 + q * 8;
      const bool kok = (k0 < NROIS);
      v8s bhi[4], blo[4];
      #pragma unroll
      for (int nt = 0; nt < 4; ++nt) {
        #pragma unroll
        for (int i = 0; i < 8; ++i) {
          float f = kok ? cw[(k0 + i) * HID + nt * 16 + ml] : 0.f;
          unsigned hb = bf16_rne(f);
          float lo = f - __uint_as_float(hb << 16);
          bhi[nt][i] = (short)hb;
          blo[nt][i] = (short)(__float_as_uint(lo) >> 16);
        }
      }
      #pragma unroll
      for (int mi = 0; mi < 2; ++mi) {
        if (mts[mi] >= 0) {
          const int row = mts[mi] * 16 + ml;
          v8s ahi, alo;
          if (kok && row < NPG) {
            const float* px = x + (size_t)(base + row) * NROIS + k0;
            const float4 f0 = *(const float4*)px;
            const float4 f1 = *(const float4*)(px + 4);
            const float ff[8] = {f0.x, f0.y, f0.z, f0.w, f1.x, f1.y, f1.z, f1.w};
            #pragma unroll
            for (int i = 0; i < 8; ++i) {
              unsigned u = __float_as_uint(ff[i]);
              unsigned hb = u >> 16;
              float lo = ff[i] - __uint_as_float(hb << 16);
              ahi[i] = (short)hb;
              alo[i] = (short)(__float_as_uint(lo) >> 16);
            }
          } else {
            #pragma unroll
            for (int i = 0; i < 8; ++i) { ahi[i] = 0; alo[i] = 0; }
          }
          #pragma unroll
          for (int nt = 0; nt < 4; ++nt) {
            acc[mi][nt] = __builtin_amdgcn_mfma_f32_16x16x32_bf16(ahi, blo[nt], acc[mi][nt], 0, 0, 0);
            acc[mi][nt] = __builtin_amdgcn_mfma_f32_16x16x32_bf16(alo, bhi[nt], acc[mi][nt], 0, 0, 0);
            acc[mi][nt] = __builtin_amdgcn_mfma_f32_16x16x32_bf16(ahi, bhi[nt], acc[mi][nt], 0, 0, 0);
          }
        }
      }
    }
    #pragma unroll
    for (int mi = 0; mi < 2; ++mi) {
      if (mts[mi] >= 0) {
        #pragma unroll
        for (int r = 0; r < 4; ++r) {
          const int row = mts[mi] * 16 + q * 4 + r;
          if (row < NPG) {
            const float dv = s.dinv[row];
            #pragma unroll
            for (int nt = 0; nt < 4; ++nt)
              s.hpT[(nt * 16 + ml) * HPITCH + row] =
                  (unsigned short)bf16_rne(dv * acc[mi][nt][r]);
          }
        }
      }
    }
  }
  __syncthreads();

  {
    int mts[2];
    mts[0] = w;
    mts[1] = (w < 5) ? 8 + w : -1;
    v4f acc2[2][4];
    #pragma unroll
    for (int a = 0; a < 2; ++a)
      #pragma unroll
      for (int b = 0; b < 4; ++b)
        acc2[a][b] = (v4f){0.f, 0.f, 0.f, 0.f};

    for (int kt = 0; kt < 7; ++kt) {
      const int k0 = kt * 32 + q * 8;
      v8s bf[4];
      #pragma unroll
      for (int nt = 0; nt < 4; ++nt)
        bf[nt] = *(const v8s*)&s.hpT[(nt * 16 + ml) * HPITCH + k0];
      #pragma unroll
      for (int mi = 0; mi < 2; ++mi) {
        if (mts[mi] >= 0) {
          const int row = mts[mi] * 16 + ml;
          const uint2 dd = *(const uint2*)&s.adj[row * APITCH + k0];
          v8s af;
          #pragma unroll
          for (int i = 0; i < 4; ++i) {
            af[i]     = (short)(__float_as_uint((float)((dd.x >> (8 * i)) & 0xffu)) >> 16);
            af[i + 4] = (short)(__float_as_uint((float)((dd.y >> (8 * i)) & 0xffu)) >> 16);
          }
          #pragma unroll
          for (int nt = 0; nt < 4; ++nt)
            acc2[mi][nt] = __builtin_amdgcn_mfma_f32_16x16x32_bf16(af, bf[nt], acc2[mi][nt], 0, 0, 0);
        }
      }
    }

    float cbv[4];
    #pragma unroll
    for (int nt = 0; nt < 4; ++nt) cbv[nt] = cb[nt * 16 + ml];
    float mx[4] = {0.f, 0.f, 0.f, 0.f};
    #pragma unroll
    for (int mi = 0; mi < 2; ++mi) {
      if (mts[mi] >= 0) {
        #pragma unroll
        for (int r = 0; r < 4; ++r) {
          const int row = mts[mi] * 16 + q * 4 + r;
          if (row < NPG) {
            const float dv = s.dinv[row];
            #pragma unroll
            for (int nt = 0; nt < 4; ++nt) {
              float v = fmaxf(fmaf(dv, acc2[mi][nt][r], cbv[nt]), 0.f);
              mx[nt] = fmaxf(mx[nt], v);
            }
          }
        }
      }
    }
    #pragma unroll
    for (int nt = 0; nt < 4; ++nt) {
      mx[nt] = fmaxf(mx[nt], __shfl_xor(mx[nt], 16));
      mx[nt] = fmaxf(mx[nt], __shfl_xor(mx[nt], 32));
    }
    if (q == 0 && (lane >> 5) == 0) {
      #pragma unroll
      for (int nt = 0; nt < 4; ++nt)
        atomicMax(&s.pool[nt * 16 + ml], __float_as_int(mx[nt]));
    }
  }
  __syncthreads();

  if (tid < HID) {
    const float xp = __int_as_float(s.pool[tid]);
    out[NUM_GRAPHS * OUTC + g * HID + tid] = xp;
    float p0 = xp * lw[tid * 2 + 0];
    float p1 = xp * lw[tid * 2 + 1];
    #pragma unroll
    for (int off = 32; off > 0; off >>= 1) {
      p0 += __shfl_down(p0, off);
      p1 += __shfl_down(p1, off);
    }
    if (tid == 0) {
      out[g * OUTC + 0] = p0 + lb[0];
      out[g * OUTC + 1] = p1 + lb[1];
    }
  }
}

extern "C" void kernel_launch(void* const* d_in, const int* in_sizes, int n_in,
                              void* d_out, int out_size, void* d_ws, size_t ws_size,
                              hipStream_t stream) {
  const float* x  = (const float*)d_in[0];
  const int*   ei = (const int*)d_in[1];
  // d_in[2] = batch (node/200 by construction; unused)
  const float* cw = (const float*)d_in[3];
  const float* cb = (const float*)d_in[4];
  const float* lw = (const float*)d_in[5];
  const float* lb = (const float*)d_in[6];
  const int Etot = in_sizes[1] / 2;

  if (ws_size >= WS_NEEDED) {
    unsigned short* wimg = (unsigned short*)d_ws;
    prep_wimg<<<(WIMG_ELEMS + 255) / 256, 256, 0, stream>>>(cw, wimg);
    gcn_fused7<<<NUM_GRAPHS, 512, 0, stream>>>(x, ei, wimg, cb, lw, lb,
                                               (float*)d_out, Etot);
  } else {
    gcn_fused_fb<<<NUM_GRAPHS, 512, 0, stream>>>(x, ei, cw, cb, lw, lb,
                                                 (float*)d_out, Etot);
  }
}

// Round 5
// 145.235 us; speedup vs baseline: 1.1052x; 1.0836x over previous
//
#include <hip/hip_runtime.h>

#define NUM_GRAPHS 512
#define NPG 200      // nodes per graph
#define EPG 3200     // edges per graph
#define NROIS 200    // input feature dim
#define HID 64
#define OUTC 2
#define APITCH 232   // adjacency row pitch (bytes) = 58 dw
#define HPITCH 232   // hpTl row pitch (elements); 464 B = 29*16 -> b128-aligned rows
#define WIMG_ELEMS (7 * 4 * 2 * 64 * 8)   // 28672 ushorts (W hi/lo frag image)
#define WS_NEEDED ((size_t)WIMG_ELEMS * 2)

typedef short v8s __attribute__((ext_vector_type(8)));
typedef float v4f __attribute__((ext_vector_type(4)));

__device__ __forceinline__ unsigned bf16_rne(float f) {
  unsigned u = __float_as_uint(f);
  return (u + 0x7fffu + ((u >> 16) & 1u)) >> 16;
}

// ============ prep: W -> bf16 hi/lo fragment-order image ============
__global__ void prep_wimg(const float* __restrict__ cw, unsigned short* __restrict__ wimg) {
  int idx = blockIdx.x * 256 + threadIdx.x;
  if (idx >= WIMG_ELEMS) return;
  int i    = idx & 7;
  int lane = (idx >> 3) & 63;
  int hl   = (idx >> 9) & 1;
  int nt   = (idx >> 10) & 3;
  int kt   = idx >> 12;
  int k  = kt * 32 + (lane >> 4) * 8 + i;
  int ch = nt * 16 + (lane & 15);
  float f = (k < NROIS) ? cw[k * HID + ch] : 0.f;
  unsigned hi = bf16_rne(f);
  float lo = f - __uint_as_float(hi << 16);
  wimg[idx] = hl ? (unsigned short)(__float_as_uint(lo) >> 16) : (unsigned short)hi;
}

// ============ fused kernel v8 ============
// v5 structure + W-tile staged in LDS once per block per kt (global_load_lds,
// double-buffered, 8KB/tile) instead of per-wave L2 loads: block wimg traffic
// 448KB -> 57KB (chip-wide 229MB -> 29MB per iteration). Costs one syncthreads
// per kt (v4 proved per-kt barriers affordable). Numerics identical to v5.
// LDS: 48256 (adj) + 29696 (hpTl | wbuf 16KB) + 800 + 800 + 256
//    = 79808 B -> 2 blocks/CU (16 waves).
struct __align__(16) Smem2 {
  unsigned char adj[208 * APITCH];        // (A+I) counts as bytes
  union {
    unsigned short hpTl[HID * HPITCH];    // bf16 dinv[src]*h[src][ch] (post-GEMM1)
    unsigned int wbuf[2][2048];           // 2 x 8KB W-tile double buffer (GEMM1)
  } u;
  int cnt[NPG];                           // in-degree (edges only; +1 for self-loop)
  float dinv[NPG];
  int pool[HID];
};

__device__ __forceinline__ v8s tobf16(const float4& a, const float4& b) {
  v8s r;
  r[0] = (short)bf16_rne(a.x); r[1] = (short)bf16_rne(a.y);
  r[2] = (short)bf16_rne(a.z); r[3] = (short)bf16_rne(a.w);
  r[4] = (short)bf16_rne(b.x); r[5] = (short)bf16_rne(b.y);
  r[6] = (short)bf16_rne(b.z); r[7] = (short)bf16_rne(b.w);
  return r;
}

// stage W tile kt (8KB) into wbuf[buf]: each thread DMAs one 16B chunk.
// LDS dest is wave-uniform base (+lane*16 by HW); global src is per-lane.
__device__ __forceinline__ void stageW(Smem2& s, const unsigned short* __restrict__ wimg,
                                       int kt, int buf, int w, int lane) {
  const char* gp = (const char*)wimg + (size_t)kt * 8192 + (size_t)(w * 64 + lane) * 16;
  unsigned char* lp = (unsigned char*)&s.u.wbuf[buf][0] + w * 1024;
  __builtin_amdgcn_global_load_lds(
      (const __attribute__((address_space(1))) unsigned int*)gp,
      (__attribute__((address_space(3))) unsigned int*)lp, 16, 0, 0);
}

// load the wave's x fragment floats for K-tile kt: lane (mi) reads 8 consecutive
// floats x[node][kt*32 + q*8 .. +8).  kt=6,q>=1 would run past col 200 -> zero-fill.
__device__ __forceinline__ void xfetch(const float* __restrict__ x, int base,
                                       int kt, int q, const int* mts, const int* nrow,
                                       float4 xa[2][2]) {
  const int k0 = kt * 32 + q * 8;
  const bool ok = (k0 + 8 <= NROIS);
  #pragma unroll
  for (int mi = 0; mi < 2; ++mi) {
    if (mts[mi] >= 0) {
      if (ok) {
        const float* px = x + (size_t)(base + nrow[mi]) * NROIS + k0;
        xa[mi][0] = *(const float4*)px;
        xa[mi][1] = *(const float4*)(px + 4);
      } else {
        xa[mi][0] = make_float4(0.f, 0.f, 0.f, 0.f);
        xa[mi][1] = make_float4(0.f, 0.f, 0.f, 0.f);
      }
    }
  }
}

__global__ __launch_bounds__(512, 4)
void gcn_fused8(const float* __restrict__ x,
                const int* __restrict__ ei,
                const unsigned short* __restrict__ wimg,
                const float* __restrict__ cb,
                const float* __restrict__ lw,
                const float* __restrict__ lb,
                float* __restrict__ out,
                int Etot) {
  __shared__ Smem2 s;
  const int g = blockIdx.x;
  const int tid = threadIdx.x;
  const int base = g * NPG;
  const int ebase = g * EPG;
  const int lane = tid & 63;
  const int w = __builtin_amdgcn_readfirstlane(tid >> 6);  // 0..7
  const int ml = tid & 15;
  const int q  = (tid >> 4) & 3;

  int mts[2];
  mts[0] = w;
  mts[1] = (w < 5) ? 8 + w : -1;
  int nrow[2];                       // clamped row index for x loads (junk discarded)
  #pragma unroll
  for (int mi = 0; mi < 2; ++mi) {
    int node = mts[mi] * 16 + ml;
    nrow[mi] = (node < NPG) ? node : 0;
  }

  // ---- startup: issue edge loads + x-tile0 + W-tile0 DMA; zero adj/cnt/pool ----
  int esrc[7], edst[7];
  #pragma unroll
  for (int r = 0; r < 7; ++r) {
    int e = tid + r * 512;
    esrc[r] = -1; edst[r] = 0;
    if (e < EPG) {
      esrc[r] = ei[ebase + e] - base;
      edst[r] = ei[Etot + ebase + e] - base;
    }
  }
  float4 xa[2][2];
  xfetch(x, base, 0, q, mts, nrow, xa);
  stageW(s, wimg, 0, 0, w, lane);           // W[0] DMA; completed by the barrier below
  {
    uint4* z = (uint4*)s.adj;
    const uint4 z4 = {0u, 0u, 0u, 0u};
    #pragma unroll
    for (int i = 0; i < 6; ++i) {
      int idx = tid + i * 512;
      if (idx < (208 * APITCH) / 16) z[idx] = z4;
    }
    if (tid < NPG) s.cnt[tid] = 0;
    if (tid < HID) s.pool[tid] = 0;   // relu >= 0 -> 0 is identity for max
  }
  __syncthreads();   // zeroes visible; W[0]/x[0] drained (full vmcnt drain)

  // ---- scatter (A+I) counts + in-degree (fire-and-forget ds atomics; they drain
  //      at the first in-loop barrier, long before adj/cnt are read) ----
  {
    unsigned* adjW = (unsigned*)s.adj;
    #pragma unroll
    for (int r = 0; r < 7; ++r) {
      if (esrc[r] >= 0) {
        int idx = edst[r] * APITCH + esrc[r];
        atomicAdd(&adjW[idx >> 2], 1u << ((idx & 3) * 8));
        atomicAdd(&s.cnt[edst[r]], 1);
      }
    }
    if (tid < NPG) {                      // self-loop diagonal (degree handled as cnt+1)
      int idx = tid * APITCH + tid;
      atomicAdd(&adjW[idx >> 2], 1u << ((idx & 3) * 8));
    }
  }

  // ---- GEMM1: H = X @ W  (x direct-from-global; W from LDS double buffer) ----
  v4f acc[2][4];
  #pragma unroll
  for (int a = 0; a < 2; ++a)
    #pragma unroll
    for (int b = 0; b < 4; ++b)
      acc[a][b] = (v4f){0.f, 0.f, 0.f, 0.f};

  for (int kt = 0; kt < 7; ++kt) {
    const int cur = kt & 1;
    // DMA next W tile into the other buffer (other buf's readers passed a barrier)
    if (kt < 6) stageW(s, wimg, kt + 1, cur ^ 1, w, lane);
    // convert current x fragments (loads drained at previous barrier)
    v8s xh2[2];
    #pragma unroll
    for (int mi = 0; mi < 2; ++mi)
      if (mts[mi] >= 0) xh2[mi] = tobf16(xa[mi][0], xa[mi][1]);
    if (kt < 6) xfetch(x, base, kt + 1, q, mts, nrow, xa);   // in flight this iter

    // read this kt's W fragments from LDS (contiguous 1KB per fragment id)
    const unsigned short* wb = (const unsigned short*)&s.u.wbuf[cur][0];
    v8s whi[4], wlo[4];
    #pragma unroll
    for (int nt = 0; nt < 4; ++nt) {
      whi[nt] = *(const v8s*)(wb + (size_t)((nt * 2 + 0) * 64 + lane) * 8);
      wlo[nt] = *(const v8s*)(wb + (size_t)((nt * 2 + 1) * 64 + lane) * 8);
    }
    #pragma unroll
    for (int mi = 0; mi < 2; ++mi) {
      if (mts[mi] >= 0) {
        #pragma unroll
        for (int nt = 0; nt < 4; ++nt) {
          acc[mi][nt] = __builtin_amdgcn_mfma_f32_16x16x32_bf16(wlo[nt], xh2[mi], acc[mi][nt], 0, 0, 0);
          acc[mi][nt] = __builtin_amdgcn_mfma_f32_16x16x32_bf16(whi[nt], xh2[mi], acc[mi][nt], 0, 0, 0);
        }
      }
    }
    __syncthreads();   // W[kt+1] DMA + x[kt+1] complete; wbuf swap safe
  }

  // ---- dinv table (for epilogue2) + pad-zero hpTl cols [200,232) + epilogue1 ----
  if (tid < NPG) s.dinv[tid] = rsqrtf((float)(s.cnt[tid] + 1));
  {
    int ch = tid >> 3, grp = tid & 7;
    *(uint2*)&s.u.hpTl[ch * HPITCH + 200 + grp * 4] = (uint2){0u, 0u};
  }
  #pragma unroll
  for (int mi = 0; mi < 2; ++mi) {
    if (mts[mi] >= 0) {
      const int node = mts[mi] * 16 + ml;
      if (node < NPG) {
        const float dv = rsqrtf((float)(s.cnt[node] + 1));   // bitwise == s.dinv[node]
        #pragma unroll
        for (int nt = 0; nt < 4; ++nt) {
          #pragma unroll
          for (int r = 0; r < 4; ++r) {
            const int ch = nt * 16 + q * 4 + r;
            s.u.hpTl[ch * HPITCH + node] = (unsigned short)bf16_rne(dv * acc[mi][nt][r]);
          }
        }
      }
    }
  }
  __syncthreads();

  // ---- GEMM2: AGG = (A+I) @ hp (counts exact in bf16) ----
  {
    v4f acc2[2][4];
    #pragma unroll
    for (int a = 0; a < 2; ++a)
      #pragma unroll
      for (int b = 0; b < 4; ++b)
        acc2[a][b] = (v4f){0.f, 0.f, 0.f, 0.f};

    for (int kt = 0; kt < 7; ++kt) {
      const int k0 = kt * 32 + q * 8;

      v8s bf[4];
      #pragma unroll
      for (int nt = 0; nt < 4; ++nt)
        bf[nt] = *(const v8s*)&s.u.hpTl[(nt * 16 + ml) * HPITCH + k0];

      #pragma unroll
      for (int mi = 0; mi < 2; ++mi) {
        if (mts[mi] >= 0) {
          const int row = mts[mi] * 16 + ml;
          const uint2 dd = *(const uint2*)&s.adj[row * APITCH + k0];
          v8s af;
          #pragma unroll
          for (int i = 0; i < 4; ++i) {
            af[i]     = (short)(__float_as_uint((float)((dd.x >> (8 * i)) & 0xffu)) >> 16);
            af[i + 4] = (short)(__float_as_uint((float)((dd.y >> (8 * i)) & 0xffu)) >> 16);
          }
          #pragma unroll
          for (int nt = 0; nt < 4; ++nt)
            acc2[mi][nt] = __builtin_amdgcn_mfma_f32_16x16x32_bf16(af, bf[nt], acc2[mi][nt], 0, 0, 0);
        }
      }
    }

    // epilogue2: relu(dinv[dst]*agg + cb) -> max-pool
    float cbv[4];
    #pragma unroll
    for (int nt = 0; nt < 4; ++nt) cbv[nt] = cb[nt * 16 + ml];
    float mx[4] = {0.f, 0.f, 0.f, 0.f};
    #pragma unroll
    for (int mi = 0; mi < 2; ++mi) {
      if (mts[mi] >= 0) {
        #pragma unroll
        for (int r = 0; r < 4; ++r) {
          const int row = mts[mi] * 16 + q * 4 + r;
          if (row < NPG) {
            const float dv = s.dinv[row];
            #pragma unroll
            for (int nt = 0; nt < 4; ++nt) {
              float v = fmaxf(fmaf(dv, acc2[mi][nt][r], cbv[nt]), 0.f);
              mx[nt] = fmaxf(mx[nt], v);
            }
          }
        }
      }
    }
    #pragma unroll
    for (int nt = 0; nt < 4; ++nt) {
      mx[nt] = fmaxf(mx[nt], __shfl_xor(mx[nt], 16));
      mx[nt] = fmaxf(mx[nt], __shfl_xor(mx[nt], 32));
    }
    if (q == 0 && (lane >> 5) == 0) {
      #pragma unroll
      for (int nt = 0; nt < 4; ++nt)
        atomicMax(&s.pool[nt * 16 + ml], __float_as_int(mx[nt]));
    }
  }
  __syncthreads();

  // ---- write x_pool and out ----
  if (tid < HID) {
    const float xp = __int_as_float(s.pool[tid]);
    out[NUM_GRAPHS * OUTC + g * HID + tid] = xp;
    float p0 = xp * lw[tid * 2 + 0];
    float p1 = xp * lw[tid * 2 + 1];
    #pragma unroll
    for (int off = 32; off > 0; off >>= 1) {
      p0 += __shfl_down(p0, off);
      p1 += __shfl_down(p1, off);
    }
    if (tid == 0) {
      out[g * OUTC + 0] = p0 + lb[0];
      out[g * OUTC + 1] = p1 + lb[1];
    }
  }
}

// ============ fallback (ws too small): fused kernel, inline W convert ============
struct __align__(16) SmemF {
  unsigned char adj[208 * APITCH];
  unsigned short hpT[HID * HPITCH];
  float dinv[NPG];
  int cnt[NPG];
  int pool[HID];
};

__global__ __launch_bounds__(512, 4)
void gcn_fused_fb(const float* __restrict__ x,
                  const int* __restrict__ ei,
                  const float* __restrict__ cw,
                  const float* __restrict__ cb,
                  const float* __restrict__ lw,
                  const float* __restrict__ lb,
                  float* __restrict__ out,
                  int Etot) {
  __shared__ SmemF s;
  const int g = blockIdx.x;
  const int tid = threadIdx.x;
  const int base = g * NPG;
  const int ebase = g * EPG;
  const int lane = tid & 63;
  const int w = __builtin_amdgcn_readfirstlane(tid >> 6);
  const int ml = tid & 15;
  const int q  = (tid >> 4) & 3;

  {
    uint4* z = (uint4*)&s;
    const uint4 z4 = {0u, 0u, 0u, 0u};
    #pragma unroll
    for (int i = 0; i < 10; ++i) {
      int idx = tid + i * 512;
      if (idx < (208 * APITCH + HID * HPITCH * 2) / 16) z[idx] = z4;
    }
    if (tid < NPG) s.cnt[tid] = 0;
    if (tid < HID) s.pool[tid] = 0;
  }
  __syncthreads();

  int esrc[7], edst[7];
  #pragma unroll
  for (int r = 0; r < 7; ++r) {
    int e = tid + r * 512;
    esrc[r] = -1; edst[r] = 0;
    if (e < EPG) {
      esrc[r] = ei[ebase + e] - base;
      edst[r] = ei[Etot + ebase + e] - base;
      atomicAdd(&s.cnt[edst[r]], 1);
    }
  }
  __syncthreads();

  if (tid < NPG) s.dinv[tid] = rsqrtf((float)(s.cnt[tid] + 1));

  {
    unsigned* adjW = (unsigned*)s.adj;
    #pragma unroll
    for (int r = 0; r < 7; ++r) {
      if (esrc[r] >= 0) {
        int idx = edst[r] * APITCH + esrc[r];
        atomicAdd(&adjW[idx >> 2], 1u << ((idx & 3) * 8));
      }
    }
    if (tid < NPG) {
      int idx = tid * APITCH + tid;
      atomicAdd(&adjW[idx >> 2], 1u << ((idx & 3) * 8));
    }
  }
  __syncthreads();

  {
    int mts[2];
    mts[0] = w;
    mts[1] = (w < 5) ? 8 + w : -1;
    v4f acc[2][4];
    #pragma unroll
    for (int a = 0; a < 2; ++a)
      #pragma unroll
      for (int b = 0; b < 4; ++b)
        acc[a][b] = (v4f){0.f, 0.f, 0.f, 0.f};

    for (int kt = 0; kt < 7; ++kt) {
      const int k0 = kt * 32 + q * 8;
      const bool kok = (k0 < NROIS);
      v8s bhi[4], blo[4];
      #pragma unroll
      for (int nt = 0; nt < 4; ++nt) {
        #pragma unroll
        for (int i = 0; i < 8; ++i) {
          float f = kok ? cw[(k0 + i) * HID + nt * 16 + ml] : 0.f;
          unsigned hb = bf16_rne(f);
          float lo = f - __uint_as_float(hb << 16);
          bhi[nt][i] = (short)hb;
          blo[nt][i] = (short)(__float_as_uint(lo) >> 16);
        }
      }
      #pragma unroll
      for (int mi = 0; mi < 2; ++mi) {
        if (mts[mi] >= 0) {
          const int row = mts[mi] * 16 + ml;
          v8s ahi, alo;
          if (kok && row < NPG) {
            const float* px = x + (size_t)(base + row) * NROIS + k0;
            const float4 f0 = *(const float4*)px;
            const float4 f1 = *(const float4*)(px + 4);
            const float ff[8] = {f0.x, f0.y, f0.z, f0.w, f1.x, f1.y, f1.z, f1.w};
            #pragma unroll
            for (int i = 0; i < 8; ++i) {
              unsigned u = __float_as_uint(ff[i]);
              unsigned hb = u >> 16;
              float lo = ff[i] - __uint_as_float(hb << 16);
              ahi[i] = (short)hb;
              alo[i] = (short)(__float_as_uint(lo) >> 16);
            }
          } else {
            #pragma unroll
            for (int i = 0; i < 8; ++i) { ahi[i] = 0; alo[i] = 0; }
          }
          #pragma unroll
          for (int nt = 0; nt < 4; ++nt) {
            acc[mi][nt] = __builtin_amdgcn_mfma_f32_16x16x32_bf16(ahi, blo[nt], acc[mi][nt], 0, 0, 0);
            acc[mi][nt] = __builtin_amdgcn_mfma_f32_16x16x32_bf16(alo, bhi[nt], acc[mi][nt], 0, 0, 0);
            acc[mi][nt] = __builtin_amdgcn_mfma_f32_16x16x32_bf16(ahi, bhi[nt], acc[mi][nt], 0, 0, 0);
          }
        }
      }
    }
    #pragma unroll
    for (int mi = 0; mi < 2; ++mi) {
      if (mts[mi] >= 0) {
        #pragma unroll
        for (int r = 0; r < 4; ++r) {
          const int row = mts[mi] * 16 + q * 4 + r;
          if (row < NPG) {
            const float dv = s.dinv[row];
            #pragma unroll
            for (int nt = 0; nt < 4; ++nt)
              s.hpT[(nt * 16 + ml) * HPITCH + row] =
                  (unsigned short)bf16_rne(dv * acc[mi][nt][r]);
          }
        }
      }
    }
  }
  __syncthreads();

  {
    int mts[2];
    mts[0] = w;
    mts[1] = (w < 5) ? 8 + w : -1;
    v4f acc2[2][4];
    #pragma unroll
    for (int a = 0; a < 2; ++a)
      #pragma unroll
      for (int b = 0; b < 4; ++b)
        acc2[a][b] = (v4f){0.f, 0.f, 0.f, 0.f};

    for (int kt = 0; kt < 7; ++kt) {
      const int k0 = kt * 32 + q * 8;
      v8s bf[4];
      #pragma unroll
      for (int nt = 0; nt < 4; ++nt)
        bf[nt] = *(const v8s*)&s.hpT[(nt * 16 + ml) * HPITCH + k0];
      #pragma unroll
      for (int mi = 0; mi < 2; ++mi) {
        if (mts[mi] >= 0) {
          const int row = mts[mi] * 16 + ml;
          const uint2 dd = *(const uint2*)&s.adj[row * APITCH + k0];
          v8s af;
          #pragma unroll
          for (int i = 0; i < 4; ++i) {
            af[i]     = (short)(__float_as_uint((float)((dd.x >> (8 * i)) & 0xffu)) >> 16);
            af[i + 4] = (short)(__float_as_uint((float)((dd.y >> (8 * i)) & 0xffu)) >> 16);
          }
          #pragma unroll
          for (int nt = 0; nt < 4; ++nt)
            acc2[mi][nt] = __builtin_amdgcn_mfma_f32_16x16x32_bf16(af, bf[nt], acc2[mi][nt], 0, 0, 0);
        }
      }
    }

    float cbv[4];
    #pragma unroll
    for (int nt = 0; nt < 4; ++nt) cbv[nt] = cb[nt * 16 + ml];
    float mx[4] = {0.f, 0.f, 0.f, 0.f};
    #pragma unroll
    for (int mi = 0; mi < 2; ++mi) {
      if (mts[mi] >= 0) {
        #pragma unroll
        for (int r = 0; r < 4; ++r) {
          const int row = mts[mi] * 16 + q * 4 + r;
          if (row < NPG) {
            const float dv = s.dinv[row];
            #pragma unroll
            for (int nt = 0; nt < 4; ++nt) {
              float v = fmaxf(fmaf(dv, acc2[mi][nt][r], cbv[nt]), 0.f);
              mx[nt] = fmaxf(mx[nt], v);
            }
          }
        }
      }
    }
    #pragma unroll
    for (int nt = 0; nt < 4; ++nt) {
      mx[nt] = fmaxf(mx[nt], __shfl_xor(mx[nt], 16));
      mx[nt] = fmaxf(mx[nt], __shfl_xor(mx[nt], 32));
    }
    if (q == 0 && (lane >> 5) == 0) {
      #pragma unroll
      for (int nt = 0; nt < 4; ++nt)
        atomicMax(&s.pool[nt * 16 + ml], __float_as_int(mx[nt]));
    }
  }
  __syncthreads();

  if (tid < HID) {
    const float xp = __int_as_float(s.pool[tid]);
    out[NUM_GRAPHS * OUTC + g * HID + tid] = xp;
    float p0 = xp * lw[tid * 2 + 0];
    float p1 = xp * lw[tid * 2 + 1];
    #pragma unroll
    for (int off = 32; off > 0; off >>= 1) {
      p0 += __shfl_down(p0, off);
      p1 += __shfl_down(p1, off);
    }
    if (tid == 0) {
      out[g * OUTC + 0] = p0 + lb[0];
      out[g * OUTC + 1] = p1 + lb[1];
    }
  }
}

extern "C" void kernel_launch(void* const* d_in, const int* in_sizes, int n_in,
                              void* d_out, int out_size, void* d_ws, size_t ws_size,
                              hipStream_t stream) {
  const float* x  = (const float*)d_in[0];
  const int*   ei = (const int*)d_in[1];
  // d_in[2] = batch (node/200 by construction; unused)
  const float* cw = (const float*)d_in[3];
  const float* cb = (const float*)d_in[4];
  const float* lw = (const float*)d_in[5];
  const float* lb = (const float*)d_in[6];
  const int Etot = in_sizes[1] / 2;

  if (ws_size >= WS_NEEDED) {
    unsigned short* wimg = (unsigned short*)d_ws;
    prep_wimg<<<(WIMG_ELEMS + 255) / 256, 256, 0, stream>>>(cw, wimg);
    gcn_fused8<<<NUM_GRAPHS, 512, 0, stream>>>(x, ei, wimg, cb, lw, lb,
                                               (float*)d_out, Etot);
  } else {
    gcn_fused_fb<<<NUM_GRAPHS, 512, 0, stream>>>(x, ei, cw, cb, lw, lb,
                                                 (float*)d_out, Etot);
  }
}